// Round 11
// baseline (1005.057 us; speedup 1.0000x reference)
//
#include <hip/hip_runtime.h>
#include <math.h>

// leaky_current_RNN: B=128, T=512, I=4, H=512, O=3, alpha=0.5, n_reg=256.
// R11 = R10 structure (two-cohort phases, agent-scope (value|tag) u64
// exchange, pk_fma matvec) + three latency fixes:
//  1. bar_lds(): lgkmcnt(0)-only barrier -- __syncthreads drains vmcnt(0),
//     forcing every phase to wait for the previous finalize's LLC publish
//     stores to retire. The barrier only protects LDS; drop the vmem drain.
//  2. 2-deep ring poll: two same-address loads in flight, alternate
//     check/reissue -> detect granularity ~RTT/2 instead of ~1.5 RTT.
//  3. Prefetch seeding: issue the next phase's poll loads right after each
//     barrier (before finalize), hiding the LLC read under finalize/compute.

#define BB 128
#define TT 512
#define II 4
#define HH 512
#define OO 3
#define NREG_ 256

#define NTHREADS 512
#define MEMBERS 4
#define NGROUPS 64
#define NBLOCKS (NGROUPS * MEMBERS)

// d_ws layout (bytes): adat u64[2 coh][2 slot][64 g][512 col] = 1 MB
#define WS_PART  (2 * 2 * NGROUPS * HH * 8)

typedef unsigned long long u64;
typedef unsigned int u32;
typedef __attribute__((ext_vector_type(2))) float f32x2;

__device__ __forceinline__ u64 aload(const u64* p) {
    return __hip_atomic_load(p, __ATOMIC_RELAXED, __HIP_MEMORY_SCOPE_AGENT);
}
__device__ __forceinline__ void astore(u64* p, u64 v) {
    __hip_atomic_store(p, v, __ATOMIC_RELAXED, __HIP_MEMORY_SCOPE_AGENT);
}
__device__ __forceinline__ float fast_tanh(float x) {
    float ax = fabsf(x);
    float e  = __expf(2.0f * ax);
    float r  = 1.0f - 2.0f * __builtin_amdgcn_rcpf(e + 1.0f);
    return copysignf(r, x);
}
// LDS-only barrier: no vmcnt drain (publish stores stay in flight).
__device__ __forceinline__ void bar_lds() {
    asm volatile("s_waitcnt lgkmcnt(0)" ::: "memory");
    __builtin_amdgcn_sched_barrier(0);
    __builtin_amdgcn_s_barrier();
    __builtin_amdgcn_sched_barrier(0);
}

#define R16(M) M(0) M(1) M(2) M(3) M(4) M(5) M(6) M(7) \
               M(8) M(9) M(10) M(11) M(12) M(13) M(14) M(15)

// Weight pairs: w.x = W[k][memb*128+lane], w.y = W[k][memb*128+64+lane]
#define WLD(Q) \
    f32x2 w##Q##a, w##Q##b, w##Q##c, w##Q##d; \
    w##Q##a.x = Wp[(size_t)(4*Q+0)*HH]; w##Q##a.y = Wp[(size_t)(4*Q+0)*HH+64]; \
    w##Q##b.x = Wp[(size_t)(4*Q+1)*HH]; w##Q##b.y = Wp[(size_t)(4*Q+1)*HH+64]; \
    w##Q##c.x = Wp[(size_t)(4*Q+2)*HH]; w##Q##c.y = Wp[(size_t)(4*Q+2)*HH+64]; \
    w##Q##d.x = Wp[(size_t)(4*Q+3)*HH]; w##Q##d.y = Wp[(size_t)(4*Q+3)*HH+64];

// acc = (colA, colB) for ONE row: row-scalar broadcast via op_sel_hi[0]=0.
#define KSTEP(K, W) { \
    u32 s_ = __builtin_amdgcn_readlane(__float_as_uint(ar), (K)); \
    u64 ss = (u64)s_; \
    asm("v_pk_fma_f32 %0, %1, %2, %0 op_sel_hi:[0,1,1]" \
        : "+v"(acc) : "s"(ss), "v"(W)); }

#define MV(Q) KSTEP(4*Q+0, w##Q##a) KSTEP(4*Q+1, w##Q##b) \
              KSTEP(4*Q+2, w##Q##c) KSTEP(4*Q+3, w##Q##d)

// 2-deep ring acquire: pa/pb are in-flight copies of *pp; on exit ar holds
// the value whose tag matched.
#define ACQUIRE(pa, pb, pp, tagc, ar) { \
    u64 uu_; \
    for (;;) { \
        if (__all((u32)((pa) >> 32) == (tagc))) { uu_ = (pa); break; } \
        (pa) = aload(pp); \
        if (__all((u32)((pb) >> 32) == (tagc))) { uu_ = (pb); break; } \
        (pb) = aload(pp); \
    } \
    ar = __uint_as_float((u32)uu_); }

// adat index: ((coh*2 + slot)*NGROUPS + g)*HH + col ; word = (tanh(h) | tag)
__global__ __launch_bounds__(NTHREADS) __attribute__((amdgpu_waves_per_eu(2, 2)))
void rnn_main(const float* __restrict__ x,
              const float* __restrict__ h0,
              const float* __restrict__ W_rec,
              const float* __restrict__ W_in,
              const float* __restrict__ bias_rec,
              const float* __restrict__ bias_in,
              float* __restrict__ hidden,      // (T+1, B, H) region of d_out
              u64* __restrict__ adat,          // exchange buffer in d_ws
              float* __restrict__ partials)
{
    const int tid  = threadIdx.x;
    const int bid  = blockIdx.x;
    const int xcd  = bid & 7;
    const int onx  = bid >> 3;
    const int memb = onx & (MEMBERS - 1);
    const int g    = xcd * 8 + (onx >> 2);    // 0..63
    const int rA   = g;                       // cohort A row
    const int rB   = 64 + g;                  // cohort B row
    const int wid  = tid >> 6;                // k-window [64*wid, 64*wid+64)
    const int lane = tid & 63;

    __shared__ float sc_s[2][128][9];         // per-cohort split-k partials
    __shared__ float xbuf[2][TT * II];        // x rows (A, B)
    __shared__ float win_s[II][128];
    __shared__ float ub_s[128];
    __shared__ float red_s[NTHREADS / 64];

    // ---- one-time staging ----
    for (int idx = tid; idx < TT * II; idx += NTHREADS) {
        xbuf[0][idx] = x[(size_t)rA * (TT * II) + idx];
        xbuf[1][idx] = x[(size_t)rB * (TT * II) + idx];
    }
    if (tid < II * 128) {
        int i = tid >> 7, jj = tid & 127;
        win_s[i][jj] = W_in[i * HH + memb * 128 + jj];
    }
    if (tid < 128) {
        ub_s[tid] = bias_rec[memb * 128 + tid] + bias_in[memb * 128 + tid];
    }

    // ---- W_rec slice into registers as float2 (colA,colB) pairs ----
    const float* Wp = W_rec + (size_t)(wid * 64) * HH + memb * 128 + lane;
    R16(WLD)

    // ---- prologue: publish tanh(h0) tag 1 for both cohorts ----
    const int fj  = tid & 127;                // finalize col (tid < 128)
    const int fjg = memb * 128 + fj;
    float hprevA = 0.0f, zprevA = 0.0f;
    float hprevB = 0.0f, zprevB = 0.0f;
    float racc = 0.0f;
    if (tid < 128) {
        hprevA = h0[(size_t)rA * HH + fjg];
        hprevB = h0[(size_t)rB * HH + fjg];
        u64 pA = (u64)__float_as_uint(fast_tanh(hprevA)) | ((u64)1u << 32);
        u64 pB = (u64)__float_as_uint(fast_tanh(hprevB)) | ((u64)1u << 32);
        astore(&adat[((size_t)(0 * 2 + 0) * NGROUPS + g) * HH + fjg], pA);
        astore(&adat[((size_t)(1 * 2 + 0) * NGROUPS + g) * HH + fjg], pB);
        hidden[(size_t)rA * HH + fjg] = hprevA;
        hidden[(size_t)rB * HH + fjg] = hprevB;
    }

    // per-lane poll addresses (cohort base + k index); slot toggles +/- NGROUPS*HH
    const size_t kidx = (size_t)wid * 64 + lane;
    const u64* ppA = adat + ((size_t)(0 * 2 + 0) * NGROUPS + g) * HH + kidx;
    const u64* ppB = adat + ((size_t)(1 * 2 + 0) * NGROUPS + g) * HH + kidx;

    // seed cohort-A ring for t=0
    u64 pA_a = aload(ppA), pA_b = aload(ppA);
    u64 pB_a = 0, pB_b = 0;

#pragma unroll 1
    for (int t = 0; t < TT; ++t) {
        const int slot  = t & 1;
        const int slot2 = (t + 1) & 1;
        const u32 tagc  = (u32)(t + 1);
        const u64 tagp  = ((u64)(t + 2) << 32);
        const u64* pA_addr = ppA + (size_t)slot * (NGROUPS * HH);
        const u64* pB_addr = ppB + (size_t)slot * (NGROUPS * HH);

        // ================= PHASE A =================
        {
            float ar;
            ACQUIRE(pA_a, pA_b, pA_addr, tagc, ar)
            f32x2 acc = {0.0f, 0.0f};
            R16(MV)
            sc_s[0][lane][wid]      = acc.x;
            sc_s[0][lane + 64][wid] = acc.y;
        }
        bar_lds();
        // prefetch cohort B (published one full phase ago -> likely visible)
        pB_a = aload(pB_addr);
        pB_b = aload(pB_addr);
        if (tid < 128) {
            float q0 = sc_s[0][fj][0], q1 = sc_s[0][fj][1];
            float q2 = sc_s[0][fj][2], q3 = sc_s[0][fj][3];
            float q4 = sc_s[0][fj][4], q5 = sc_s[0][fj][5];
            float q6 = sc_s[0][fj][6], q7 = sc_s[0][fj][7];
            float z = ((q0 + q1) + (q2 + q3)) + ((q4 + q5) + (q6 + q7));
            z += ub_s[fj];
            const float* xr = &xbuf[0][t * II];
            z = fmaf(xr[0], win_s[0][fj], z);
            z = fmaf(xr[1], win_s[1][fj], z);
            z = fmaf(xr[2], win_s[2][fj], z);
            z = fmaf(xr[3], win_s[3][fj], z);
            float hn = 0.5f * hprevA + 0.5f * z;
            u64 pv = (u64)__float_as_uint(fast_tanh(hn)) | tagp;
            astore(&adat[((size_t)(0 * 2 + slot2) * NGROUPS + g) * HH + fjg], pv);
            hidden[(size_t)(t + 1) * BB * HH + (size_t)rA * HH + fjg] = hn;
            if (fjg < NREG_) {
                float d1 = hn - hprevA;
                racc = fmaf(d1, d1, racc);
                if (t > 0) { float d2 = z - zprevA; racc = fmaf(d2, d2, racc); }
                zprevA = z;
            }
            hprevA = hn;
        }

        // ================= PHASE B =================
        {
            float ar;
            ACQUIRE(pB_a, pB_b, pB_addr, tagc, ar)
            f32x2 acc = {0.0f, 0.0f};
            R16(MV)
            sc_s[1][lane][wid]      = acc.x;
            sc_s[1][lane + 64][wid] = acc.y;
        }
        bar_lds();
        // prefetch cohort A for t+1 (published during phase A's finalize)
        {
            const u64* pA_next = ppA + (size_t)slot2 * (NGROUPS * HH);
            pA_a = aload(pA_next);
            pA_b = aload(pA_next);
        }
        if (tid < 128) {
            float q0 = sc_s[1][fj][0], q1 = sc_s[1][fj][1];
            float q2 = sc_s[1][fj][2], q3 = sc_s[1][fj][3];
            float q4 = sc_s[1][fj][4], q5 = sc_s[1][fj][5];
            float q6 = sc_s[1][fj][6], q7 = sc_s[1][fj][7];
            float z = ((q0 + q1) + (q2 + q3)) + ((q4 + q5) + (q6 + q7));
            z += ub_s[fj];
            const float* xr = &xbuf[1][t * II];
            z = fmaf(xr[0], win_s[0][fj], z);
            z = fmaf(xr[1], win_s[1][fj], z);
            z = fmaf(xr[2], win_s[2][fj], z);
            z = fmaf(xr[3], win_s[3][fj], z);
            float hn = 0.5f * hprevB + 0.5f * z;
            u64 pv = (u64)__float_as_uint(fast_tanh(hn)) | tagp;
            astore(&adat[((size_t)(1 * 2 + slot2) * NGROUPS + g) * HH + fjg], pv);
            hidden[(size_t)(t + 1) * BB * HH + (size_t)rB * HH + fjg] = hn;
            if (fjg < NREG_) {
                float d1 = hn - hprevB;
                racc = fmaf(d1, d1, racc);
                if (t > 0) { float d2 = z - zprevB; racc = fmaf(d2, d2, racc); }
                zprevB = z;
            }
            hprevB = hn;
        }
    }

    // ---- block-reduce reg partial (stored by ROLE for determinism) ----
    for (int off = 32; off; off >>= 1) racc += __shfl_down(racc, off);
    if ((tid & 63) == 0) red_s[tid >> 6] = racc;
    __syncthreads();
    if (tid == 0) {
        float s = 0.0f;
        for (int i = 0; i < NTHREADS / 64; ++i) s += red_s[i];
        partials[g * MEMBERS + memb] = s;
    }
}

// outputs[b][t][:] = hidden[t+1][b][:] @ W_out   (one wave per (b,t))
__global__ __launch_bounds__(256)
void rnn_out(const float* __restrict__ hidden,
             const float* __restrict__ W_out,
             float* __restrict__ outputs)
{
    __shared__ float wout_s[HH * OO];
    const int tid = threadIdx.x;
    for (int i = tid; i < HH * OO; i += 256) wout_s[i] = W_out[i];
    __syncthreads();

    const int gid  = blockIdx.x * 4 + (tid >> 6);
    const int lane = tid & 63;
    const int b = gid >> 9;
    const int t = gid & (TT - 1);
    const float* hp = hidden + (size_t)(t + 1) * BB * HH + (size_t)b * HH;

    float o0 = 0.0f, o1 = 0.0f, o2 = 0.0f;
#pragma unroll
    for (int q = 0; q < 8; ++q) {
        int k = lane + 64 * q;
        float hv = hp[k];
        o0 = fmaf(hv, wout_s[k * 3 + 0], o0);
        o1 = fmaf(hv, wout_s[k * 3 + 1], o1);
        o2 = fmaf(hv, wout_s[k * 3 + 2], o2);
    }
    for (int off = 32; off; off >>= 1) {
        o0 += __shfl_down(o0, off);
        o1 += __shfl_down(o1, off);
        o2 += __shfl_down(o2, off);
    }
    if (lane == 0) {
        float* op = outputs + (size_t)(b * TT + t) * OO;
        op[0] = o0; op[1] = o1; op[2] = o2;
    }
}

__global__ __launch_bounds__(256)
void rnn_tcr(const float* __restrict__ partials, float* __restrict__ tcr)
{
    __shared__ float red[4];
    const int tid = threadIdx.x;
    float v = partials[tid];
    for (int off = 32; off; off >>= 1) v += __shfl_down(v, off);
    if ((tid & 63) == 0) red[tid >> 6] = v;
    __syncthreads();
    if (tid == 0) {
        float s = red[0] + red[1] + red[2] + red[3];
        *tcr = s * (1.0f / ((float)TT * (float)BB * (float)NREG_));
    }
}

extern "C" void kernel_launch(void* const* d_in, const int* in_sizes, int n_in,
                              void* d_out, int out_size, void* d_ws, size_t ws_size,
                              hipStream_t stream)
{
    (void)in_sizes; (void)n_in; (void)out_size; (void)ws_size;

    const float* x     = (const float*)d_in[0];
    const float* h0    = (const float*)d_in[1];
    const float* W_rec = (const float*)d_in[2];
    const float* W_in  = (const float*)d_in[3];
    const float* W_out = (const float*)d_in[4];
    const float* brec  = (const float*)d_in[5];
    const float* bin   = (const float*)d_in[6];

    float* out     = (float*)d_out;
    float* outputs = out;
    float* hidden  = out + (size_t)BB * TT * OO;
    float* tcr     = out + (size_t)BB * TT * OO + (size_t)(TT + 1) * BB * HH;

    u64*   adat     = (u64*)d_ws;
    float* partials = (float*)((char*)d_ws + WS_PART);

    // zero exchange-buffer tags every call (graph replays reuse d_ws)
    (void)hipMemsetAsync(d_ws, 0, WS_PART, stream);

    void* args[] = { (void*)&x, (void*)&h0, (void*)&W_rec, (void*)&W_in,
                     (void*)&brec, (void*)&bin, (void*)&hidden,
                     (void*)&adat, (void*)&partials };
    (void)hipLaunchCooperativeKernel((const void*)rnn_main,
                                     dim3(NBLOCKS), dim3(NTHREADS),
                                     args, 0, stream);

    rnn_out<<<dim3((BB * TT) / 4), dim3(256), 0, stream>>>(hidden, W_out, outputs);
    rnn_tcr<<<dim3(1), dim3(256), 0, stream>>>(partials, tcr);
}